// Round 10
// baseline (266.299 us; speedup 1.0000x reference)
//
#include <hip/hip_runtime.h>
#include <hip/hip_bf16.h>

typedef _Float16 half8 __attribute__((ext_vector_type(8)));
typedef _Float16 half4 __attribute__((ext_vector_type(4)));
typedef float floatx4 __attribute__((ext_vector_type(4)));

#define LOG2E 1.44269504088896340736f

__device__ __forceinline__ half8 cvt8r(floatx4 a, floatx4 b) {
    half8 h;
    h[0] = (_Float16)a[0]; h[1] = (_Float16)a[1]; h[2] = (_Float16)a[2]; h[3] = (_Float16)a[3];
    h[4] = (_Float16)b[0]; h[5] = (_Float16)b[1]; h[6] = (_Float16)b[2]; h[7] = (_Float16)b[3];
    return h;
}

// ---------------- K1: transpose + convert W (f32 [512x512]) -> WT fp16 [n][k] ----------------
__global__ __launch_bounds__(256) void transpose_w_kernel(
        const float* __restrict__ Wq, const float* __restrict__ Wk,
        const float* __restrict__ Wv, const float* __restrict__ Wo,
        _Float16* __restrict__ out) {
    const float* W = (blockIdx.z == 0) ? Wq : (blockIdx.z == 1) ? Wk : (blockIdx.z == 2) ? Wv : Wo;
    _Float16* o = out + (size_t)blockIdx.z * 512 * 512;
    __shared__ __align__(16) _Float16 t[64][72];
    int r0 = blockIdx.x * 64, c0 = blockIdx.y * 64;
    int tid = threadIdx.x;
    for (int i = 0; i < 2; i++) {
        int f = i * 256 + tid;
        int row = f >> 3, seg = f & 7;
        const float* p = W + (size_t)(r0 + row) * 512 + c0 + seg * 8;
        *(half8*)&t[row][seg * 8] = cvt8r(*(const floatx4*)p, *(const floatx4*)(p + 4));
    }
    __syncthreads();
    for (int i = 0; i < 2; i++) {
        int f = i * 256 + tid;
        int crow = f >> 3, seg = f & 7;
        half8 hv;
        for (int j = 0; j < 8; j++) hv[j] = t[seg * 8 + j][crow];
        *(half8*)(o + (size_t)(c0 + crow) * 512 + r0 + seg * 8) = hv;
    }
}

// ---------------- K2: QKV projection GEMM, 64x128 tiles; dead K/V blocks skipped ----------------
__global__ __launch_bounds__(256) void gemm_qkv_kernel(
        const float* __restrict__ Xq, const float* __restrict__ Xk, const float* __restrict__ Xv,
        const _Float16* __restrict__ WTall,
        const float* __restrict__ bq, const float* __restrict__ bk, const float* __restrict__ bv,
        const int* __restrict__ vlens,
        _Float16* __restrict__ qo, _Float16* __restrict__ ko2, _Float16* __restrict__ vto) {
    int z = blockIdx.z;
    int mBase = blockIdx.x * 64, nBase = blockIdx.y * 128;

    if (z >= 1) {
        int b_ = mBase >> 11, s0 = mBase & 2047;
        int L = vlens[b_];
        if (s0 >= L && !(z == 2 && L == 0)) return;
    }

    const float* X = (z == 0) ? Xq : (z == 1) ? Xk : Xv;
    const _Float16* BT = WTall + (size_t)z * 512 * 512;
    const float* bias = (z == 0) ? bq : (z == 1) ? bk : bv;

    __shared__ __align__(16) _Float16 Asm[64][72];
    __shared__ __align__(16) _Float16 Bsm[128][72];

    int tid = threadIdx.x;
    int wave = tid >> 6, lane = tid & 63;
    int lrow = lane & 15, quad = lane >> 4;
    int mrow = wave * 16 + lrow;

    const floatx4 fz = {0.f, 0.f, 0.f, 0.f};
    floatx4 acc[8];
    for (int i = 0; i < 8; i++) acc[i] = fz;

    int arow[2], aseg[2], brow[4], bseg[4];
    for (int i = 0; i < 2; i++) { int f = i * 256 + tid; arow[i] = f >> 3; aseg[i] = f & 7; }
    for (int i = 0; i < 4; i++) { int f = i * 256 + tid; brow[i] = f >> 3; bseg[i] = f & 7; }

    floatx4 areg[2][2];
    half8 breg[4];
    for (int i = 0; i < 2; i++) {
        const float* pa = X + (size_t)(mBase + arow[i]) * 512 + aseg[i] * 8;
        areg[i][0] = *(const floatx4*)pa;
        areg[i][1] = *(const floatx4*)(pa + 4);
    }
    for (int i = 0; i < 4; i++)
        breg[i] = *(const half8*)(BT + (size_t)(nBase + brow[i]) * 512 + bseg[i] * 8);

    for (int kb = 0; kb < 512; kb += 64) {
        for (int i = 0; i < 2; i++) *(half8*)&Asm[arow[i]][aseg[i] * 8] = cvt8r(areg[i][0], areg[i][1]);
        for (int i = 0; i < 4; i++) *(half8*)&Bsm[brow[i]][bseg[i] * 8] = breg[i];
        __syncthreads();
        if (kb + 64 < 512) {
            int kn = kb + 64;
            for (int i = 0; i < 2; i++) {
                const float* pa = X + (size_t)(mBase + arow[i]) * 512 + kn + aseg[i] * 8;
                areg[i][0] = *(const floatx4*)pa;
                areg[i][1] = *(const floatx4*)(pa + 4);
            }
            for (int i = 0; i < 4; i++)
                breg[i] = *(const half8*)(BT + (size_t)(nBase + brow[i]) * 512 + kn + bseg[i] * 8);
        }
        for (int kc = 0; kc < 2; kc++) {
            int ko_ = kc * 32 + quad * 8;
            half8 a = *(const half8*)&Asm[mrow][ko_];
            for (int nt = 0; nt < 8; nt++) {
                half8 b = *(const half8*)&Bsm[nt * 16 + lrow][ko_];
                acc[nt] = __builtin_amdgcn_mfma_f32_16x16x32_f16(a, b, acc[nt], 0, 0, 0);
            }
        }
        __syncthreads();
    }

    if (z == 2) {
        for (int nt = 0; nt < 8; nt++) {
            int gc = nBase + nt * 16 + lrow;
            float bb = bias[gc];
            int h = gc >> 6, hd = gc & 63;
            int gr = mBase + wave * 16 + quad * 4;
            int b_ = gr >> 11, s = gr & 2047;
            half4 hv;
            for (int r = 0; r < 4; r++) hv[r] = (_Float16)(acc[nt][r] + bb);
            *(half4*)(vto + (((size_t)(b_ * 8 + h) * 64 + hd) * 2048 + s)) = hv;
        }
    } else {
        _Float16* out = (z == 0) ? qo : ko2;
        for (int nt = 0; nt < 8; nt++) {
            int gc = nBase + nt * 16 + lrow;
            float bb = bias[gc];
            int h = gc >> 6, hd = gc & 63;
            for (int r = 0; r < 4; r++) {
                int gr = mBase + wave * 16 + quad * 4 + r;
                int b_ = gr >> 11, s = gr & 2047;
                out[(((size_t)b_ * 8 + h) * 2048 + s) * 64 + hd] = (_Float16)(acc[nt][r] + bb);
            }
        }
    }
}

// ---------------- K3: flash attention v7: LDS-free, barrier-free, BM=128 ----------------
// 4 waves x 32 q-rows. K-tile (8KB) and V^T-tile (8KB) served from L1 (all waves load
// identical fragment addresses). Fixed-max softmax, register P, ones-fragment row sums.
__global__ __launch_bounds__(256) void attn_kernel(
        const _Float16* __restrict__ qws, const _Float16* __restrict__ kws, const _Float16* __restrict__ vtws,
        const int* __restrict__ vlens, _Float16* __restrict__ aout) {
    int idx = blockIdx.x;
    int b = ((idx & 3) + (idx >> 7)) & 3;     // bijective per (h,qb); mixes batches across CUs
    int h = (idx >> 2) & 7;
    int q0 = ((idx >> 5) & 15) * 128;
    int bh = b * 8 + h;
    int L = vlens[b];
    bool uni = (L == 0);
    int nkt = uni ? 32 : ((L + 63) >> 6);
    int nfull = uni ? 0 : (L >> 6);

    int tid = threadIdx.x;
    int w = tid >> 6, lane = tid & 63;
    int lrow = lane & 15, quad = lane >> 4;

    const _Float16* qbase = qws + ((size_t)bh * 2048 + q0) * 64;
    const _Float16* kbase = kws + (size_t)bh * 2048 * 64;
    const _Float16* vtbase = vtws + (size_t)bh * 64 * 2048;

    half8 qf[2][2];    // [qt][kc], softmax scale folded in
    for (int qt = 0; qt < 2; qt++)
        for (int kc = 0; kc < 2; kc++) {
            qf[qt][kc] = *(const half8*)(qbase + (w * 32 + qt * 16 + lrow) * 64 + kc * 32 + quad * 8);
            qf[qt][kc] = qf[qt][kc] * (_Float16)(0.125f * LOG2E);
        }

    // B-fragment of the all-ones V^T row (row-sum column): n=lrow, any k
    half4 onesf;
    {
        _Float16 o1 = (lrow == 0) ? (_Float16)1.0f : (_Float16)0.0f;
        onesf[0] = o1; onesf[1] = o1; onesf[2] = o1; onesf[3] = o1;
    }

    const floatx4 fz = {0.f, 0.f, 0.f, 0.f};
    floatx4 oacc[2][5];
    for (int qt = 0; qt < 2; qt++) for (int nt = 0; nt < 5; nt++) oacc[qt][nt] = fz;

    for (int kt = 0; kt < nkt; kt++) {
        const _Float16* ktile = kbase + (size_t)kt * 4096;
        const _Float16* vttile = vtbase + kt * 64;

        // K fragments straight from global (L1-resident: all 4 waves read same addrs)
        half8 kf[2][4];
        for (int kc = 0; kc < 2; kc++)
            for (int km = 0; km < 4; km++)
                kf[kc][km] = *(const half8*)(ktile + (km * 16 + lrow) * 64 + kc * 32 + quad * 8);
        // V^T fragments (issued early to overlap with QK MFMAs)
        half4 bvf[4][4];
        for (int km = 0; km < 4; km++)
            for (int nt = 0; nt < 4; nt++)
                bvf[km][nt] = *(const half4*)(vttile + (size_t)(nt * 16 + lrow) * 2048 + km * 16 + quad * 4);

        // S^T = K·(Q·c)^T : C-layout (key = km*16+quad*4+r, q = lrow)
        floatx4 sacc[2][4];
        for (int qt = 0; qt < 2; qt++) for (int km = 0; km < 4; km++) sacc[qt][km] = fz;
        for (int kc = 0; kc < 2; kc++)
            for (int km = 0; km < 4; km++) {
                sacc[0][km] = __builtin_amdgcn_mfma_f32_16x16x32_f16(kf[kc][km], qf[0][kc], sacc[0][km], 0, 0, 0);
                sacc[1][km] = __builtin_amdgcn_mfma_f32_16x16x32_f16(kf[kc][km], qf[1][kc], sacc[1][km], 0, 0, 0);
            }

        half4 pf[2][4];
        if (kt < nfull) {
            for (int qt = 0; qt < 2; qt++)
                for (int km = 0; km < 4; km++)
                    for (int r = 0; r < 4; r++)
                        pf[qt][km][r] = (_Float16)exp2f(sacc[qt][km][r]);
        } else {
            int kb0 = kt * 64 + quad * 4;
            for (int km = 0; km < 4; km++) {
                int kb = kb0 + km * 16;
                for (int qt = 0; qt < 2; qt++)
                    for (int r = 0; r < 4; r++) {
                        float p = uni ? 1.0f : ((kb + r < L) ? exp2f(sacc[qt][km][r]) : 0.0f);
                        pf[qt][km][r] = (_Float16)p;
                    }
            }
        }

        // PV: D[q][hd] += P[q][key16] * V[key16][hd]; nt==4 via register ones-fragment
        for (int km = 0; km < 4; km++) {
            for (int nt = 0; nt < 4; nt++) {
                oacc[0][nt] = __builtin_amdgcn_mfma_f32_16x16x16f16(pf[0][km], bvf[km][nt], oacc[0][nt], 0, 0, 0);
                oacc[1][nt] = __builtin_amdgcn_mfma_f32_16x16x16f16(pf[1][km], bvf[km][nt], oacc[1][nt], 0, 0, 0);
            }
            oacc[0][4] = __builtin_amdgcn_mfma_f32_16x16x16f16(pf[0][km], onesf, oacc[0][4], 0, 0, 0);
            oacc[1][4] = __builtin_amdgcn_mfma_f32_16x16x16f16(pf[1][km], onesf, oacc[1][4], 0, 0, 0);
        }
    }

    for (int qt = 0; qt < 2; qt++) {
        float inv[4];
        for (int r = 0; r < 4; r++)
            inv[r] = 1.0f / __shfl(oacc[qt][4][r], quad << 4, 64);
        for (int nt = 0; nt < 4; nt++) {
            for (int r = 0; r < 4; r++) {
                int s = q0 + w * 32 + qt * 16 + quad * 4 + r;
                aout[((size_t)b * 2048 + s) * 512 + h * 64 + nt * 16 + lrow] =
                    (_Float16)(oacc[qt][nt][r] * inv[r]);
            }
        }
    }
}

// ---------------- K4: output projection, 64x128 tiles (reg-prefetch dbuf) -> f32 ----------------
__global__ __launch_bounds__(256) void gemm_out_kernel(
        const _Float16* __restrict__ A, const _Float16* __restrict__ BT,
        const float* __restrict__ bias, float* __restrict__ out) {
    __shared__ __align__(16) _Float16 Asm[64][72];
    __shared__ __align__(16) _Float16 Bsm[128][72];

    int tid = threadIdx.x;
    int wave = tid >> 6, lane = tid & 63;
    int lrow = lane & 15, quad = lane >> 4;
    int mBase = blockIdx.x * 64, nBase = blockIdx.y * 128;
    int mrow = wave * 16 + lrow;

    const floatx4 fz = {0.f, 0.f, 0.f, 0.f};
    floatx4 acc[8];
    for (int i = 0; i < 8; i++) acc[i] = fz;

    int arow[2], aseg[2], brow[4], bseg[4];
    for (int i = 0; i < 2; i++) { int f = i * 256 + tid; arow[i] = f >> 3; aseg[i] = f & 7; }
    for (int i = 0; i < 4; i++) { int f = i * 256 + tid; brow[i] = f >> 3; bseg[i] = f & 7; }

    half8 areg[2], breg[4];
    for (int i = 0; i < 2; i++)
        areg[i] = *(const half8*)(A + (size_t)(mBase + arow[i]) * 512 + aseg[i] * 8);
    for (int i = 0; i < 4; i++)
        breg[i] = *(const half8*)(BT + (size_t)(nBase + brow[i]) * 512 + bseg[i] * 8);

    for (int kb = 0; kb < 512; kb += 64) {
        for (int i = 0; i < 2; i++) *(half8*)&Asm[arow[i]][aseg[i] * 8] = areg[i];
        for (int i = 0; i < 4; i++) *(half8*)&Bsm[brow[i]][bseg[i] * 8] = breg[i];
        __syncthreads();
        if (kb + 64 < 512) {
            int kn = kb + 64;
            for (int i = 0; i < 2; i++)
                areg[i] = *(const half8*)(A + (size_t)(mBase + arow[i]) * 512 + kn + aseg[i] * 8);
            for (int i = 0; i < 4; i++)
                breg[i] = *(const half8*)(BT + (size_t)(nBase + brow[i]) * 512 + kn + bseg[i] * 8);
        }
        for (int kc = 0; kc < 2; kc++) {
            int ko_ = kc * 32 + quad * 8;
            half8 a = *(const half8*)&Asm[mrow][ko_];
            for (int nt = 0; nt < 8; nt++) {
                half8 b = *(const half8*)&Bsm[nt * 16 + lrow][ko_];
                acc[nt] = __builtin_amdgcn_mfma_f32_16x16x32_f16(a, b, acc[nt], 0, 0, 0);
            }
        }
        __syncthreads();
    }

    for (int nt = 0; nt < 8; nt++) {
        int gc = nBase + nt * 16 + lrow;
        float bb = bias[gc];
        for (int r = 0; r < 4; r++) {
            int gr = mBase + wave * 16 + quad * 4 + r;
            out[(size_t)gr * 512 + gc] = acc[nt][r] + bb;
        }
    }
}

extern "C" void kernel_launch(void* const* d_in, const int* in_sizes, int n_in,
                              void* d_out, int out_size, void* d_ws, size_t ws_size,
                              hipStream_t stream) {
    const float* Q  = (const float*)d_in[0];
    const float* K  = (const float*)d_in[1];
    const float* V  = (const float*)d_in[2];
    const int*   VL = (const int*)d_in[3];
    const float* Wq = (const float*)d_in[4];
    const float* bq = (const float*)d_in[5];
    const float* Wk = (const float*)d_in[6];
    const float* bk = (const float*)d_in[7];
    const float* Wv = (const float*)d_in[8];
    const float* bv = (const float*)d_in[9];
    const float* Wo = (const float*)d_in[10];
    const float* bo = (const float*)d_in[11];

    char* ws = (char*)d_ws;
    _Float16* WT   = (_Float16*)ws;                                  // 2 MiB
    _Float16* qws  = (_Float16*)(ws + (size_t)(2)  * 1024 * 1024);   // 8 MiB [bh][s][hd]
    _Float16* kws  = (_Float16*)(ws + (size_t)(10) * 1024 * 1024);   // 8 MiB [bh][s][hd]
    _Float16* aout = (_Float16*)(ws + (size_t)(18) * 1024 * 1024);   // 8 MiB [8192,512]
    _Float16* vtws = (_Float16*)(ws + (size_t)(26) * 1024 * 1024);   // 8 MiB [bh][hd][s]

    transpose_w_kernel<<<dim3(8, 8, 4), 256, 0, stream>>>(Wq, Wk, Wv, Wo, WT);
    gemm_qkv_kernel<<<dim3(128, 4, 3), 256, 0, stream>>>(Q, K, V, WT, bq, bk, bv, VL, qws, kws, vtws);
    attn_kernel<<<dim3(512, 1, 1), 256, 0, stream>>>(qws, kws, vtws, VL, aout);
    gemm_out_kernel<<<dim3(128, 4, 1), 256, 0, stream>>>(aout, WT + (size_t)3 * 512 * 512, bo, (float*)d_out);
}

// Round 11
// 191.076 us; speedup vs baseline: 1.3937x; 1.3937x over previous
//
#include <hip/hip_runtime.h>
#include <hip/hip_bf16.h>

typedef _Float16 half8 __attribute__((ext_vector_type(8)));
typedef _Float16 half4 __attribute__((ext_vector_type(4)));
typedef float floatx4 __attribute__((ext_vector_type(4)));

#define LOG2E 1.44269504088896340736f

__device__ __forceinline__ half8 cvt8r(floatx4 a, floatx4 b) {
    half8 h;
    h[0] = (_Float16)a[0]; h[1] = (_Float16)a[1]; h[2] = (_Float16)a[2]; h[3] = (_Float16)a[3];
    h[4] = (_Float16)b[0]; h[5] = (_Float16)b[1]; h[6] = (_Float16)b[2]; h[7] = (_Float16)b[3];
    return h;
}

// ---------------- K1: transpose + convert W (f32 [512x512]) -> WT fp16 [n][k] ----------------
__global__ __launch_bounds__(256) void transpose_w_kernel(
        const float* __restrict__ Wq, const float* __restrict__ Wk,
        const float* __restrict__ Wv, const float* __restrict__ Wo,
        _Float16* __restrict__ out) {
    const float* W = (blockIdx.z == 0) ? Wq : (blockIdx.z == 1) ? Wk : (blockIdx.z == 2) ? Wv : Wo;
    _Float16* o = out + (size_t)blockIdx.z * 512 * 512;
    __shared__ __align__(16) _Float16 t[64][72];
    int r0 = blockIdx.x * 64, c0 = blockIdx.y * 64;
    int tid = threadIdx.x;
    for (int i = 0; i < 2; i++) {
        int f = i * 256 + tid;
        int row = f >> 3, seg = f & 7;
        const float* p = W + (size_t)(r0 + row) * 512 + c0 + seg * 8;
        *(half8*)&t[row][seg * 8] = cvt8r(*(const floatx4*)p, *(const floatx4*)(p + 4));
    }
    __syncthreads();
    for (int i = 0; i < 2; i++) {
        int f = i * 256 + tid;
        int crow = f >> 3, seg = f & 7;
        half8 hv;
        for (int j = 0; j < 8; j++) hv[j] = t[seg * 8 + j][crow];
        *(half8*)(o + (size_t)(c0 + crow) * 512 + r0 + seg * 8) = hv;
    }
}

// ---------------- K2: QKV projection GEMM, 64x128 tiles; dead K/V blocks skipped ----------------
__global__ __launch_bounds__(256) void gemm_qkv_kernel(
        const float* __restrict__ Xq, const float* __restrict__ Xk, const float* __restrict__ Xv,
        const _Float16* __restrict__ WTall,
        const float* __restrict__ bq, const float* __restrict__ bk, const float* __restrict__ bv,
        const int* __restrict__ vlens,
        _Float16* __restrict__ qo, _Float16* __restrict__ ko2, _Float16* __restrict__ vto) {
    int z = blockIdx.z;
    int mBase = blockIdx.x * 64, nBase = blockIdx.y * 128;

    if (z >= 1) {
        int b_ = mBase >> 11, s0 = mBase & 2047;
        int L = vlens[b_];
        if (s0 >= L && !(z == 2 && L == 0)) return;
    }

    const float* X = (z == 0) ? Xq : (z == 1) ? Xk : Xv;
    const _Float16* BT = WTall + (size_t)z * 512 * 512;
    const float* bias = (z == 0) ? bq : (z == 1) ? bk : bv;

    __shared__ __align__(16) _Float16 Asm[64][72];
    __shared__ __align__(16) _Float16 Bsm[128][72];

    int tid = threadIdx.x;
    int wave = tid >> 6, lane = tid & 63;
    int lrow = lane & 15, quad = lane >> 4;
    int mrow = wave * 16 + lrow;

    const floatx4 fz = {0.f, 0.f, 0.f, 0.f};
    floatx4 acc[8];
    for (int i = 0; i < 8; i++) acc[i] = fz;

    int arow[2], aseg[2], brow[4], bseg[4];
    for (int i = 0; i < 2; i++) { int f = i * 256 + tid; arow[i] = f >> 3; aseg[i] = f & 7; }
    for (int i = 0; i < 4; i++) { int f = i * 256 + tid; brow[i] = f >> 3; bseg[i] = f & 7; }

    floatx4 areg[2][2];
    half8 breg[4];
    for (int i = 0; i < 2; i++) {
        const float* pa = X + (size_t)(mBase + arow[i]) * 512 + aseg[i] * 8;
        areg[i][0] = *(const floatx4*)pa;
        areg[i][1] = *(const floatx4*)(pa + 4);
    }
    for (int i = 0; i < 4; i++)
        breg[i] = *(const half8*)(BT + (size_t)(nBase + brow[i]) * 512 + bseg[i] * 8);

    for (int kb = 0; kb < 512; kb += 64) {
        for (int i = 0; i < 2; i++) *(half8*)&Asm[arow[i]][aseg[i] * 8] = cvt8r(areg[i][0], areg[i][1]);
        for (int i = 0; i < 4; i++) *(half8*)&Bsm[brow[i]][bseg[i] * 8] = breg[i];
        __syncthreads();
        if (kb + 64 < 512) {
            int kn = kb + 64;
            for (int i = 0; i < 2; i++) {
                const float* pa = X + (size_t)(mBase + arow[i]) * 512 + kn + aseg[i] * 8;
                areg[i][0] = *(const floatx4*)pa;
                areg[i][1] = *(const floatx4*)(pa + 4);
            }
            for (int i = 0; i < 4; i++)
                breg[i] = *(const half8*)(BT + (size_t)(nBase + brow[i]) * 512 + kn + bseg[i] * 8);
        }
        for (int kc = 0; kc < 2; kc++) {
            int ko_ = kc * 32 + quad * 8;
            half8 a = *(const half8*)&Asm[mrow][ko_];
            for (int nt = 0; nt < 8; nt++) {
                half8 b = *(const half8*)&Bsm[nt * 16 + lrow][ko_];
                acc[nt] = __builtin_amdgcn_mfma_f32_16x16x32_f16(a, b, acc[nt], 0, 0, 0);
            }
        }
        __syncthreads();
    }

    if (z == 2) {
        for (int nt = 0; nt < 8; nt++) {
            int gc = nBase + nt * 16 + lrow;
            float bb = bias[gc];
            int h = gc >> 6, hd = gc & 63;
            int gr = mBase + wave * 16 + quad * 4;
            int b_ = gr >> 11, s = gr & 2047;
            half4 hv;
            for (int r = 0; r < 4; r++) hv[r] = (_Float16)(acc[nt][r] + bb);
            *(half4*)(vto + (((size_t)(b_ * 8 + h) * 64 + hd) * 2048 + s)) = hv;
        }
    } else {
        _Float16* out = (z == 0) ? qo : ko2;
        for (int nt = 0; nt < 8; nt++) {
            int gc = nBase + nt * 16 + lrow;
            float bb = bias[gc];
            int h = gc >> 6, hd = gc & 63;
            for (int r = 0; r < 4; r++) {
                int gr = mBase + wave * 16 + quad * 4 + r;
                int b_ = gr >> 11, s = gr & 2047;
                out[(((size_t)b_ * 8 + h) * 2048 + s) * 64 + hd] = (_Float16)(acc[nt][r] + bb);
            }
        }
    }
}

// ---------------- K3: flash attention v8: BM=32, 2 waves, grid 2048 (16 waves/CU) ----------------
// LDS staging (shared by both waves), register P, register ones-fragment, reg-prefetch.
__global__ __launch_bounds__(128) void attn_kernel(
        const _Float16* __restrict__ qws, const _Float16* __restrict__ kws, const _Float16* __restrict__ vtws,
        const int* __restrict__ vlens, _Float16* __restrict__ aout) {
    int idx = blockIdx.x;
    int b = ((idx & 3) + (idx >> 8)) & 3;   // bijective; consecutive idx and idx+256k span batches
    int h = (idx >> 2) & 7;
    int q0 = ((idx >> 5) & 63) * 32;
    int bh = b * 8 + h;
    int L = vlens[b];
    bool uni = (L == 0);
    int nkt = uni ? 32 : ((L + 63) >> 6);
    int nfull = uni ? 0 : (L >> 6);

    int tid = threadIdx.x;
    int w = tid >> 6, lane = tid & 63;
    int lrow = lane & 15, quad = lane >> 4;

    __shared__ __align__(16) _Float16 ksm[64][72];
    __shared__ __align__(16) _Float16 vtsm[64][72];

    const _Float16* qbase = qws + ((size_t)bh * 2048 + q0) * 64;
    const _Float16* kbase = kws + (size_t)bh * 2048 * 64;
    const _Float16* vtbase = vtws + (size_t)bh * 64 * 2048;

    half8 qf[2];   // wave's 16 q-rows; softmax scale folded in
    for (int kc = 0; kc < 2; kc++) {
        qf[kc] = *(const half8*)(qbase + (w * 16 + lrow) * 64 + kc * 32 + quad * 8);
        qf[kc] = qf[kc] * (_Float16)(0.125f * LOG2E);
    }

    half4 onesf;   // B-fragment of all-ones V^T row (row-sum column)
    {
        _Float16 o1 = (lrow == 0) ? (_Float16)1.0f : (_Float16)0.0f;
        onesf[0] = o1; onesf[1] = o1; onesf[2] = o1; onesf[3] = o1;
    }

    const floatx4 fz = {0.f, 0.f, 0.f, 0.f};
    floatx4 oacc[5];
    for (int nt = 0; nt < 5; nt++) oacc[nt] = fz;

    int srow[4], sseg[4];
    for (int i = 0; i < 4; i++) { int f = i * 128 + tid; srow[i] = f >> 3; sseg[i] = f & 7; }
    half8 kreg[4], vreg[4];
    for (int i = 0; i < 4; i++) {
        kreg[i] = *(const half8*)(kbase + (i * 128 + tid) * 8);
        vreg[i] = *(const half8*)(vtbase + (size_t)srow[i] * 2048 + sseg[i] * 8);
    }

    for (int kt = 0; kt < nkt; kt++) {
        for (int i = 0; i < 4; i++) {
            *(half8*)&ksm[srow[i]][sseg[i] * 8]  = kreg[i];
            *(half8*)&vtsm[srow[i]][sseg[i] * 8] = vreg[i];
        }
        __syncthreads();
        if (kt + 1 < nkt) {
            const _Float16* ktn = kbase + (size_t)(kt + 1) * 4096;
            const _Float16* vtn = vtbase + (kt + 1) * 64;
            for (int i = 0; i < 4; i++) {
                kreg[i] = *(const half8*)(ktn + (i * 128 + tid) * 8);
                vreg[i] = *(const half8*)(vtn + (size_t)srow[i] * 2048 + sseg[i] * 8);
            }
        }

        // S^T = K·(Q·c)^T : C-layout (key = km*16+quad*4+r, q = lrow)
        floatx4 sacc[4];
        for (int km = 0; km < 4; km++) sacc[km] = fz;
        for (int kc = 0; kc < 2; kc++) {
            int ko_ = kc * 32 + quad * 8;
            for (int km = 0; km < 4; km++) {
                half8 kf = *(const half8*)&ksm[km * 16 + lrow][ko_];
                sacc[km] = __builtin_amdgcn_mfma_f32_16x16x32_f16(kf, qf[kc], sacc[km], 0, 0, 0);
            }
        }

        half4 pf[4];
        if (kt < nfull) {
            for (int km = 0; km < 4; km++)
                for (int r = 0; r < 4; r++)
                    pf[km][r] = (_Float16)exp2f(sacc[km][r]);
        } else {
            int kb0 = kt * 64 + quad * 4;
            for (int km = 0; km < 4; km++) {
                int kb = kb0 + km * 16;
                for (int r = 0; r < 4; r++) {
                    float p = uni ? 1.0f : ((kb + r < L) ? exp2f(sacc[km][r]) : 0.0f);
                    pf[km][r] = (_Float16)p;
                }
            }
        }

        // PV: D[q][hd] += P[q][key16] * V[key16][hd]; sums via register ones-fragment
        for (int km = 0; km < 4; km++) {
            int kk = km * 16 + quad * 4;
            for (int nt = 0; nt < 4; nt++) {
                half4 bvf = *(const half4*)&vtsm[nt * 16 + lrow][kk];
                oacc[nt] = __builtin_amdgcn_mfma_f32_16x16x16f16(pf[km], bvf, oacc[nt], 0, 0, 0);
            }
            oacc[4] = __builtin_amdgcn_mfma_f32_16x16x16f16(pf[km], onesf, oacc[4], 0, 0, 0);
        }
        __syncthreads();
    }

    float inv[4];
    for (int r = 0; r < 4; r++)
        inv[r] = 1.0f / __shfl(oacc[4][r], quad << 4, 64);

    for (int nt = 0; nt < 4; nt++) {
        for (int r = 0; r < 4; r++) {
            int s = q0 + w * 16 + quad * 4 + r;
            aout[((size_t)b * 2048 + s) * 512 + h * 64 + nt * 16 + lrow] =
                (_Float16)(oacc[nt][r] * inv[r]);
        }
    }
}

// ---------------- K4: output projection, 64x128 tiles (reg-prefetch dbuf) -> f32 ----------------
__global__ __launch_bounds__(256) void gemm_out_kernel(
        const _Float16* __restrict__ A, const _Float16* __restrict__ BT,
        const float* __restrict__ bias, float* __restrict__ out) {
    __shared__ __align__(16) _Float16 Asm[64][72];
    __shared__ __align__(16) _Float16 Bsm[128][72];

    int tid = threadIdx.x;
    int wave = tid >> 6, lane = tid & 63;
    int lrow = lane & 15, quad = lane >> 4;
    int mBase = blockIdx.x * 64, nBase = blockIdx.y * 128;
    int mrow = wave * 16 + lrow;

    const floatx4 fz = {0.f, 0.f, 0.f, 0.f};
    floatx4 acc[8];
    for (int i = 0; i < 8; i++) acc[i] = fz;

    int arow[2], aseg[2], brow[4], bseg[4];
    for (int i = 0; i < 2; i++) { int f = i * 256 + tid; arow[i] = f >> 3; aseg[i] = f & 7; }
    for (int i = 0; i < 4; i++) { int f = i * 256 + tid; brow[i] = f >> 3; bseg[i] = f & 7; }

    half8 areg[2], breg[4];
    for (int i = 0; i < 2; i++)
        areg[i] = *(const half8*)(A + (size_t)(mBase + arow[i]) * 512 + aseg[i] * 8);
    for (int i = 0; i < 4; i++)
        breg[i] = *(const half8*)(BT + (size_t)(nBase + brow[i]) * 512 + bseg[i] * 8);

    for (int kb = 0; kb < 512; kb += 64) {
        for (int i = 0; i < 2; i++) *(half8*)&Asm[arow[i]][aseg[i] * 8] = areg[i];
        for (int i = 0; i < 4; i++) *(half8*)&Bsm[brow[i]][bseg[i] * 8] = breg[i];
        __syncthreads();
        if (kb + 64 < 512) {
            int kn = kb + 64;
            for (int i = 0; i < 2; i++)
                areg[i] = *(const half8*)(A + (size_t)(mBase + arow[i]) * 512 + kn + aseg[i] * 8);
            for (int i = 0; i < 4; i++)
                breg[i] = *(const half8*)(BT + (size_t)(nBase + brow[i]) * 512 + kn + bseg[i] * 8);
        }
        for (int kc = 0; kc < 2; kc++) {
            int ko_ = kc * 32 + quad * 8;
            half8 a = *(const half8*)&Asm[mrow][ko_];
            for (int nt = 0; nt < 8; nt++) {
                half8 b = *(const half8*)&Bsm[nt * 16 + lrow][ko_];
                acc[nt] = __builtin_amdgcn_mfma_f32_16x16x32_f16(a, b, acc[nt], 0, 0, 0);
            }
        }
        __syncthreads();
    }

    for (int nt = 0; nt < 8; nt++) {
        int gc = nBase + nt * 16 + lrow;
        float bb = bias[gc];
        for (int r = 0; r < 4; r++) {
            int gr = mBase + wave * 16 + quad * 4 + r;
            out[(size_t)gr * 512 + gc] = acc[nt][r] + bb;
        }
    }
}

extern "C" void kernel_launch(void* const* d_in, const int* in_sizes, int n_in,
                              void* d_out, int out_size, void* d_ws, size_t ws_size,
                              hipStream_t stream) {
    const float* Q  = (const float*)d_in[0];
    const float* K  = (const float*)d_in[1];
    const float* V  = (const float*)d_in[2];
    const int*   VL = (const int*)d_in[3];
    const float* Wq = (const float*)d_in[4];
    const float* bq = (const float*)d_in[5];
    const float* Wk = (const float*)d_in[6];
    const float* bk = (const float*)d_in[7];
    const float* Wv = (const float*)d_in[8];
    const float* bv = (const float*)d_in[9];
    const float* Wo = (const float*)d_in[10];
    const float* bo = (const float*)d_in[11];

    char* ws = (char*)d_ws;
    _Float16* WT   = (_Float16*)ws;                                  // 2 MiB
    _Float16* qws  = (_Float16*)(ws + (size_t)(2)  * 1024 * 1024);   // 8 MiB [bh][s][hd]
    _Float16* kws  = (_Float16*)(ws + (size_t)(10) * 1024 * 1024);   // 8 MiB [bh][s][hd]
    _Float16* aout = (_Float16*)(ws + (size_t)(18) * 1024 * 1024);   // 8 MiB [8192,512]
    _Float16* vtws = (_Float16*)(ws + (size_t)(26) * 1024 * 1024);   // 8 MiB [bh][hd][s]

    transpose_w_kernel<<<dim3(8, 8, 4), 256, 0, stream>>>(Wq, Wk, Wv, Wo, WT);
    gemm_qkv_kernel<<<dim3(128, 4, 3), 256, 0, stream>>>(Q, K, V, WT, bq, bk, bv, VL, qws, kws, vtws);
    attn_kernel<<<dim3(2048, 1, 1), 128, 0, stream>>>(qws, kws, vtws, VL, aout);
    gemm_out_kernel<<<dim3(128, 4, 1), 256, 0, stream>>>(aout, WT + (size_t)3 * 512 * 512, bo, (float*)d_out);
}